// Round 10
// baseline (139.661 us; speedup 1.0000x reference)
//
#include <hip/hip_runtime.h>
#include <math.h>

#define N_NODES 50000
#define N_EDGES 800000
#define N_CLUST 5000
#define DIM     128
#define NOUT    40
#define SLOTS   64          // max in-degree kept; Poisson(16) tail beyond 64 ~1e-19
#define CSLOT   64          // max cluster size kept; multinomial(50k,5k) max ~25

// single-pass bucketized edge ingest: static per-(block,bucket) segments, LDS cursors only
#define NBKT    391                          // ceil(50000/128) dst-buckets of 128 nodes
#define BUCKB   500                          // bucketize blocks, 1600 edges each
#define EPB4    400                          // int4 per bucketize block
#define SEG     28                           // per-(block,bucket) capacity; lambda=4.1, +11 sigma

// block layout in fused_A: [bucketize 0..499) [inv 500..695) [zgemm 696..1477)
#define INV0    BUCKB
#define INVB    196
#define ZG0     (INV0 + INVB)                // 696
#define ZB      782                          // 782*4 = 3128 waves, 1 tile each >= 3125
#define GRID_A  (ZG0 + ZB)                   // 1478

typedef __attribute__((ext_vector_type(8))) short short8;
typedef __attribute__((ext_vector_type(4))) float fvec4;
typedef __attribute__((ext_vector_type(4))) int ivec4;
typedef __attribute__((ext_vector_type(4))) unsigned uvec4;

// ---------- bf16 helpers (RNE) ----------
__device__ __forceinline__ short bf16r(float v) {
    unsigned u = __float_as_uint(v);
    u = (u + 0x7FFFu + ((u >> 16) & 1u)) >> 16;
    return (short)u;
}
__device__ __forceinline__ unsigned pack_bf16x2(float a, float b) {
    unsigned ua = __float_as_uint(a);
    unsigned ub = __float_as_uint(b);
    ua = (ua + 0x7FFFu + ((ua >> 16) & 1u)) >> 16;
    ub = (ub + 0x7FFFu + ((ub >> 16) & 1u)) >> 16;
    return ua | (ub << 16);
}
__device__ __forceinline__ float2 unpack_bf16x2(unsigned v) {
    float2 r;
    r.x = __uint_as_float(v << 16);
    r.y = __uint_as_float(v & 0xFFFF0000u);
    return r;
}
__device__ __forceinline__ float4 unpack_bf16x4(uint2 v) {
    float4 r;
    r.x = __uint_as_float(v.x << 16);
    r.y = __uint_as_float(v.x & 0xFFFF0000u);
    r.z = __uint_as_float(v.y << 16);
    r.w = __uint_as_float(v.y & 0xFFFF0000u);
    return r;
}
struct f8 { float4 a, b; };
__device__ __forceinline__ f8 unpack_bf16x8(uint4 q) {
    f8 r;
    r.a.x = __uint_as_float(q.x << 16);
    r.a.y = __uint_as_float(q.x & 0xFFFF0000u);
    r.a.z = __uint_as_float(q.y << 16);
    r.a.w = __uint_as_float(q.y & 0xFFFF0000u);
    r.b.x = __uint_as_float(q.z << 16);
    r.b.y = __uint_as_float(q.z & 0xFFFF0000u);
    r.b.z = __uint_as_float(q.w << 16);
    r.b.w = __uint_as_float(q.w & 0xFFFF0000u);
    return r;
}
__device__ __forceinline__ float4 sel4(bool c, float4 v) {
    float4 r;
    r.x = c ? v.x : 0.0f; r.y = c ? v.y : 0.0f;
    r.z = c ? v.z : 0.0f; r.w = c ? v.w : 0.0f;
    return r;
}

// ---------- fused A: bucketize (0..499) | inv (500..695) | zgemm (696..1477) ----------
__global__ __launch_bounds__(256) void fused_A(const float* __restrict__ x,
                                               const int* __restrict__ esrc,
                                               const int* __restrict__ edst,
                                               const int* __restrict__ cidx,
                                               const float* __restrict__ W,
                                               int* __restrict__ ccnt,
                                               unsigned short* __restrict__ zs,
                                               unsigned short* __restrict__ cinv,
                                               int* __restrict__ gcount,
                                               unsigned* __restrict__ gbuck) {
    __shared__ int bcnt[NBKT];
    int lane = threadIdx.x & 63;
    int wv = threadIdx.x >> 6;

    if (blockIdx.x < BUCKB) {
        // ---- bucketize: SINGLE pass, LDS cursors, static segments, 0 device atomics ----
        int fb = blockIdx.x;
        const ivec4* src4 = (const ivec4*)esrc;
        const ivec4* dst4 = (const ivec4*)edst;
        int q0 = fb * EPB4;

        for (int i = threadIdx.x; i < NBKT; i += 256) bcnt[i] = 0;
        __syncthreads();

        for (int i = threadIdx.x; i < EPB4; i += 256) {
            ivec4 d4 = dst4[q0 + i];
            ivec4 s4 = src4[q0 + i];
            {
                int bk = d4.x >> 7; int pos = atomicAdd(&bcnt[bk], 1);
                if (pos < SEG) gbuck[((size_t)fb * NBKT + bk) * SEG + pos] =
                                   ((unsigned)d4.x << 16) | (unsigned)s4.x;
            }
            {
                int bk = d4.y >> 7; int pos = atomicAdd(&bcnt[bk], 1);
                if (pos < SEG) gbuck[((size_t)fb * NBKT + bk) * SEG + pos] =
                                   ((unsigned)d4.y << 16) | (unsigned)s4.y;
            }
            {
                int bk = d4.z >> 7; int pos = atomicAdd(&bcnt[bk], 1);
                if (pos < SEG) gbuck[((size_t)fb * NBKT + bk) * SEG + pos] =
                                   ((unsigned)d4.z << 16) | (unsigned)s4.z;
            }
            {
                int bk = d4.w >> 7; int pos = atomicAdd(&bcnt[bk], 1);
                if (pos < SEG) gbuck[((size_t)fb * NBKT + bk) * SEG + pos] =
                                   ((unsigned)d4.w << 16) | (unsigned)s4.w;
            }
        }
        __syncthreads();
        for (int bk = threadIdx.x; bk < NBKT; bk += 256) {
            int c = bcnt[bk];
            gcount[fb * NBKT + bk] = (c < SEG) ? c : SEG;
        }
    } else if (blockIdx.x < ZG0) {
        // ---- inverse cluster list: cinv[c][pos] = node ----
        int i = (blockIdx.x - INV0) * 256 + threadIdx.x;
        if (i < N_NODES) {
            int c = cidx[i];
            int pos = atomicAdd(&ccnt[c], 1);
            if (pos < CSLOT) cinv[c * CSLOT + pos] = (unsigned short)i;
        }
    } else {
        // ---- zgemm UNSCALED: zs[n][o] = bf16( dot(x[n], W[o]) ), 1 tile/wave ----
        int gw = (blockIdx.x - ZG0) * 4 + wv;         // 0..3127
        if (gw >= N_NODES / 16) return;
        int q = lane >> 4, r16 = lane & 15;

        short8 bfr[3][4];
        #pragma unroll
        for (int t = 0; t < 3; t++) {
            int o = t * 16 + r16;
            #pragma unroll
            for (int s = 0; s < 4; s++) {
                short8 f = {0, 0, 0, 0, 0, 0, 0, 0};
                if (o < NOUT) {
                    const float* wp = W + o * DIM + s * 32 + q * 8;
                    float4 w0 = *(const float4*)wp;
                    float4 w1 = *(const float4*)(wp + 4);
                    f[0] = bf16r(w0.x); f[1] = bf16r(w0.y);
                    f[2] = bf16r(w0.z); f[3] = bf16r(w0.w);
                    f[4] = bf16r(w1.x); f[5] = bf16r(w1.y);
                    f[6] = bf16r(w1.z); f[7] = bf16r(w1.w);
                }
                bfr[t][s] = f;
            }
        }

        int tile = gw;
        int node = tile * 16 + r16;
        short8 af[4];
        #pragma unroll
        for (int s = 0; s < 4; s++) {
            const fvec4* xp = (const fvec4*)(x + (size_t)node * DIM + s * 32 + q * 8);
            fvec4 a0 = *xp;                       // normal load: x is L3-resident
            fvec4 a1 = *(xp + 1);
            short8 f;
            f[0] = bf16r(a0.x); f[1] = bf16r(a0.y);
            f[2] = bf16r(a0.z); f[3] = bf16r(a0.w);
            f[4] = bf16r(a1.x); f[5] = bf16r(a1.y);
            f[6] = bf16r(a1.z); f[7] = bf16r(a1.w);
            af[s] = f;
        }

        fvec4 acc0 = {0, 0, 0, 0}, acc1 = {0, 0, 0, 0}, acc2 = {0, 0, 0, 0};
        #pragma unroll
        for (int s = 0; s < 4; s++) {
            acc0 = __builtin_amdgcn_mfma_f32_16x16x32_bf16(af[s], bfr[0][s], acc0, 0, 0, 0);
            acc1 = __builtin_amdgcn_mfma_f32_16x16x32_bf16(af[s], bfr[1][s], acc1, 0, 0, 0);
            acc2 = __builtin_amdgcn_mfma_f32_16x16x32_bf16(af[s], bfr[2][s], acc2, 0, 0, 0);
        }

        // normal stores: wave dirties full lines; zs read by build_scale next (keep in L2)
        #pragma unroll
        for (int r = 0; r < 4; r++) {
            int nd = tile * 16 + q * 4 + r;
            unsigned short* zrow = zs + (size_t)nd * NOUT;
            zrow[r16] = (unsigned short)bf16r(acc0[r]);
            zrow[16 + r16] = (unsigned short)bf16r(acc1[r]);
            if (r16 < 8)
                zrow[32 + r16] = (unsigned short)bf16r(acc2[r]);
        }
    }
}

// ---------- build: gather 500 segments/bucket -> slot CSR in LDS + cnt + zd scale ----------
__global__ __launch_bounds__(256) void build_scale(const unsigned* __restrict__ gbuck,
                                                   const int* __restrict__ gcount,
                                                   const uint2* __restrict__ zs2,
                                                   int* __restrict__ cnt,
                                                   unsigned short* __restrict__ slot,
                                                   uint2* __restrict__ zd2) {
    __shared__ int c128[128];
    __shared__ unsigned short sl[128 * SLOTS];   // 16 KB staged slot rows
    int tid = threadIdx.x;
    int b = blockIdx.x;                          // bucket
    if (tid < 128) c128[tid] = 0;
    __syncthreads();
    for (int sb = tid; sb < BUCKB; sb += 256) {  // ~2 segments per thread, avg 4.1 entries each
        int m = gcount[sb * NBKT + b];
        const unsigned* seg = gbuck + ((size_t)sb * NBKT + b) * SEG;
        for (int i = 0; i < m; i++) {
            unsigned e = seg[i];
            int d7 = (int)(e >> 16) & 127;
            int pos = atomicAdd(&c128[d7], 1);
            if (pos < SLOTS) sl[(d7 << 6) + pos] = (unsigned short)(e & 0xFFFFu);
        }
    }
    __syncthreads();
    // stream slot rows out coalesced, normal stores; CLAMP rows (round-6 overrun lesson)
    {
        int rows = N_NODES - (b << 7);
        if (rows > 128) rows = 128;
        int n4 = rows * (SLOTS / 8);             // 8 x uvec4 per row
        const uvec4* s4 = (const uvec4*)sl;
        uvec4* g4 = (uvec4*)(slot + ((size_t)(b << 7)) * SLOTS);
        for (int i = tid; i < n4; i += 256)
            g4[i] = s4[i];
    }
    int n0 = b << 7;
    if (tid < 128) {
        int n = n0 + tid;
        if (n < N_NODES) cnt[n] = c128[tid];
    }
    // fused scale: zd[n] = bf16( rsqrt(cnt[n]+1) * zs[n] ) for this block's 128 rows
    for (int i = tid; i < 128 * 10; i += 256) {
        int r = i / 10;
        int n = n0 + r;
        if (n < N_NODES) {
            int k = i - r * 10;
            float dn = rsqrtf((float)(c128[r] + 1));
            float4 f = unpack_bf16x4(zs2[(size_t)n * 10 + k]);
            uint2 p;
            p.x = pack_bf16x2(dn * f.x, dn * f.y);
            p.y = pack_bf16x2(dn * f.z, dn * f.w);
            zd2[(size_t)n * 10 + k] = p;
        }
    }
}

// ---------- hop1 (40-dim): 12 nodes/wave, 5 lanes x uint4, 8 gathers in flight ----------
// v1[n] = dn^2 * ( zd[n] + sum_s zd[s] )   (zd pre-scaled by dinv)
__global__ __launch_bounds__(256) void hop_all(const uint4* __restrict__ zd4,
                                               uint4* __restrict__ v14,
                                               const uint4* __restrict__ slot4,
                                               const int* __restrict__ cnt) {
    int lane = threadIdx.x & 63;
    int wv = threadIdx.x >> 6;
    int g = lane / 5;                      // 0..12 (lanes 60-63 idle)
    int k = lane - g * 5;                  // 0..4, 16B each -> 80B row
    int n = blockIdx.x * 48 + wv * 12 + g;
    if (g >= 12 || n >= N_NODES) return;
    int c = cnt[n];
    int m = (c < SLOTS) ? c : SLOTS;
    float s = 1.0f / (float)(c + 1);       // dinv^2
    f8 self = unpack_bf16x8(zd4[(size_t)n * 5 + k]);   // already dinv-scaled
    float4 aA = self.a, aB = self.b;
    float4 bA = {0, 0, 0, 0}, bB = {0, 0, 0, 0};
    const uint4* srow = slot4 + (size_t)n * 8;         // 64 slots = 8 uint4
    int j = 0;
    for (; j + 8 <= m; j += 8) {           // full chunk: 1 slot load -> 8 gathers in flight
        uint4 s8 = srow[j >> 3];
        f8 f0 = unpack_bf16x8(zd4[(size_t)(s8.x & 0xFFFFu) * 5 + k]);
        f8 f1 = unpack_bf16x8(zd4[(size_t)(s8.x >> 16) * 5 + k]);
        f8 f2 = unpack_bf16x8(zd4[(size_t)(s8.y & 0xFFFFu) * 5 + k]);
        f8 f3 = unpack_bf16x8(zd4[(size_t)(s8.y >> 16) * 5 + k]);
        f8 f4 = unpack_bf16x8(zd4[(size_t)(s8.z & 0xFFFFu) * 5 + k]);
        f8 f5 = unpack_bf16x8(zd4[(size_t)(s8.z >> 16) * 5 + k]);
        f8 f6 = unpack_bf16x8(zd4[(size_t)(s8.w & 0xFFFFu) * 5 + k]);
        f8 f7 = unpack_bf16x8(zd4[(size_t)(s8.w >> 16) * 5 + k]);
        aA = aA + ((f0.a + f1.a) + (f4.a + f5.a));
        aB = aB + ((f0.b + f1.b) + (f4.b + f5.b));
        bA = bA + ((f2.a + f3.a) + (f6.a + f7.a));
        bB = bB + ((f2.b + f3.b) + (f6.b + f7.b));
    }
    if (j < m) {                            // partial chunk: clamp idx (OOB-safe), select adds (NaN-safe)
        int rem = m - j;                    // 1..7, uniform within the 5-lane group
        uint4 s8 = srow[j >> 3];
        unsigned i0 = s8.x & 0xFFFFu;
        unsigned i1 = (rem > 1) ? (s8.x >> 16) : 0u;
        unsigned i2 = (rem > 2) ? (s8.y & 0xFFFFu) : 0u;
        unsigned i3 = (rem > 3) ? (s8.y >> 16) : 0u;
        unsigned i4 = (rem > 4) ? (s8.z & 0xFFFFu) : 0u;
        unsigned i5 = (rem > 5) ? (s8.z >> 16) : 0u;
        unsigned i6 = (rem > 6) ? (s8.w & 0xFFFFu) : 0u;
        f8 f0 = unpack_bf16x8(zd4[(size_t)i0 * 5 + k]);
        f8 f1 = unpack_bf16x8(zd4[(size_t)i1 * 5 + k]);
        f8 f2 = unpack_bf16x8(zd4[(size_t)i2 * 5 + k]);
        f8 f3 = unpack_bf16x8(zd4[(size_t)i3 * 5 + k]);
        f8 f4 = unpack_bf16x8(zd4[(size_t)i4 * 5 + k]);
        f8 f5 = unpack_bf16x8(zd4[(size_t)i5 * 5 + k]);
        f8 f6 = unpack_bf16x8(zd4[(size_t)i6 * 5 + k]);
        aA = aA + f0.a;                     // rem >= 1 always
        aB = aB + f0.b;
        bA = bA + sel4(rem > 1, f1.a) + sel4(rem > 3, f3.a) + sel4(rem > 5, f5.a);
        bB = bB + sel4(rem > 1, f1.b) + sel4(rem > 3, f3.b) + sel4(rem > 5, f5.b);
        aA = aA + sel4(rem > 2, f2.a) + sel4(rem > 4, f4.a) + sel4(rem > 6, f6.a);
        aB = aB + sel4(rem > 2, f2.b) + sel4(rem > 4, f4.b) + sel4(rem > 6, f6.b);
    }
    float4 rA = aA + bA;
    float4 rB = aB + bB;
    uint4 o;
    o.x = pack_bf16x2(s * rA.x, s * rA.y);
    o.y = pack_bf16x2(s * rA.z, s * rA.w);
    o.z = pack_bf16x2(s * rB.x, s * rB.y);
    o.w = pack_bf16x2(s * rB.z, s * rB.w);
    v14[(size_t)n * 5 + k] = o;
}

// ---------- fused hop2(rep) + bias + log_softmax + scatter to members ----------
__global__ __launch_bounds__(256) void rep_scatter(const unsigned* __restrict__ v1,
                                                   const unsigned short* __restrict__ slot,
                                                   const int* __restrict__ cnt,
                                                   const int* __restrict__ ccnt,
                                                   const unsigned short* __restrict__ cinv,
                                                   const int* __restrict__ rep_idx,
                                                   const float2* __restrict__ b2,
                                                   float2* __restrict__ out2) {
    int lane = threadIdx.x & 63;
    int wv = threadIdx.x >> 6;
    int c = blockIdx.x * 4 + wv;
    if (c >= N_CLUST) return;
    int n = rep_idx[c];
    int cn = cnt[n];
    int m = (cn < SLOTS) ? cn : SLOTS;
    float dn = rsqrtf((float)(cn + 1));
    int g = lane / 20;
    int k = lane - g * 20;
    float2 acc; acc.x = 0.0f; acc.y = 0.0f;
    if (g == 0) acc = unpack_bf16x2(v1[n * 20 + k]);   // self
    if (g < 3) {
        int base = n * SLOTS;
        for (int j = g; j < m; j += 3) {
            float2 f = unpack_bf16x2(v1[(int)slot[base + j] * 20 + k]);
            acc.x += f.x; acc.y += f.y;
        }
    }
    float t1x = __shfl(acc.x, lane + 20), t1y = __shfl(acc.y, lane + 20);
    float t2x = __shfl(acc.x, lane + 40), t2y = __shfl(acc.y, lane + 40);
    bool act = (lane < 20);
    float2 h; h.x = 0.0f; h.y = 0.0f;
    if (act) {
        float2 bb = b2[k];
        h.x = dn * (acc.x + t1x + t2x) + bb.x;
        h.y = dn * (acc.y + t1y + t2y) + bb.y;
    }
    float mx = act ? fmaxf(h.x, h.y) : -INFINITY;
    #pragma unroll
    for (int off = 32; off; off >>= 1) mx = fmaxf(mx, __shfl_xor(mx, off));
    float e = act ? (expf(h.x - mx) + expf(h.y - mx)) : 0.0f;
    #pragma unroll
    for (int off = 32; off; off >>= 1) e += __shfl_xor(e, off);
    float lg = mx + logf(e);
    float2 o; o.x = h.x - lg; o.y = h.y - lg;
    // broadcast o across the three 20-lane groups, scatter 3 members at a time
    float ox = __shfl(o.x, k);
    float oy = __shfl(o.y, k);
    int mc = ccnt[c];
    if (mc > CSLOT) mc = CSLOT;
    const unsigned short* mem = cinv + c * CSLOT;
    if (g < 3) {
        float2 ob; ob.x = ox; ob.y = oy;
        for (int idx = g; idx < mc; idx += 3) {
            int node = (int)mem[idx];
            out2[(size_t)node * 20 + k] = ob;
        }
    }
}

extern "C" void kernel_launch(void* const* d_in, const int* in_sizes, int n_in,
                              void* d_out, int out_size, void* d_ws, size_t ws_size,
                              hipStream_t stream) {
    const float* x    = (const float*)d_in[0];
    const int*   esrc = (const int*)d_in[1];
    const int*   edst = ((const int*)d_in[1]) + N_EDGES;
    const int*   cidx = (const int*)d_in[2];
    const int*   ridx = (const int*)d_in[3];
    const float* W    = (const float*)d_in[4];
    const float* b    = (const float*)d_in[5];
    float* out = (float*)d_out;

    char* ws = (char*)d_ws;
    size_t off = 0;
    auto alloc = [&](size_t bytes) { char* p = ws + off; off += (bytes + 255) & ~size_t(255); return p; };
    int*            cnt    = (int*)alloc((N_NODES + N_CLUST) * 4);
    int*            ccnt   = cnt + N_NODES;
    int*            gcount = (int*)alloc((size_t)BUCKB * NBKT * 4);                // 782 KB
    unsigned short* slot   = (unsigned short*)alloc((size_t)N_NODES * SLOTS * 2);  // 6.4 MB
    unsigned short* zs     = (unsigned short*)alloc((size_t)N_NODES * NOUT * 2);   // 4 MB
    unsigned short* zd     = (unsigned short*)alloc((size_t)N_NODES * NOUT * 2);   // 4 MB
    unsigned*       v1     = (unsigned*)alloc((size_t)N_NODES * (NOUT / 2) * 4);   // 4 MB
    unsigned short* cinv   = (unsigned short*)alloc((size_t)N_CLUST * CSLOT * 2);  // 640 KB
    unsigned*       gbuck  = (unsigned*)alloc((size_t)BUCKB * NBKT * SEG * 4);     // 21.9 MB
    (void)ws_size; (void)in_sizes; (void)n_in; (void)out_size;

    // only ccnt needs zeroing (cnt rewritten by build_scale; gcount fully rewritten by ingest)
    (void)hipMemsetAsync(ccnt, 0, N_CLUST * 4, stream);

    fused_A<<<GRID_A, 256, 0, stream>>>(x, esrc, edst, cidx, W,
                                        ccnt, zs, cinv, gcount, gbuck);
    build_scale<<<NBKT, 256, 0, stream>>>(gbuck, gcount, (const uint2*)zs,
                                          cnt, slot, (uint2*)zd);
    hop_all<<<(N_NODES + 47) / 48, 256, 0, stream>>>((const uint4*)zd, (uint4*)v1,
                                                     (const uint4*)slot, cnt);
    rep_scatter<<<(N_CLUST + 3) / 4, 256, 0, stream>>>((const unsigned*)v1, slot, cnt,
                                                       ccnt, cinv, ridx,
                                                       (const float2*)b, (float2*)out);
}

// Round 11
// 135.959 us; speedup vs baseline: 1.0272x; 1.0272x over previous
//
#include <hip/hip_runtime.h>
#include <math.h>

#define N_NODES 50000
#define N_EDGES 800000
#define N_CLUST 5000
#define DIM     128
#define NOUT    40
#define SLOTS   64          // max in-degree kept; Poisson(16) tail beyond 64 ~1e-19
#define CSLOT   64          // max cluster size kept; multinomial(50k,5k) max ~25

// bucketized edge ingest
#define NBKT    391                          // ceil(50000/128) dst-buckets of 128 nodes
#define BCAP    2560                         // per-bucket capacity (lambda=2048, +11 sigma)
#define GB_STR  16                           // gbcnt stride (1 counter per 64B line)
#define BUCKB   250                          // bucketize blocks, 3200 edges each
#define EPB4    800                          // int4 per bucketize block

// block layout in fused_A: [zgemm ZB) [inv INVB) [bucketize BUCKB)
#define ZB     782                           // 782*4 = 3128 waves, 1 tile each >= 3125
#define INVB   50
#define GRID_A (ZB + INVB + BUCKB)           // 1082

typedef __attribute__((ext_vector_type(8))) short short8;
typedef __attribute__((ext_vector_type(4))) float fvec4;
typedef __attribute__((ext_vector_type(4))) int ivec4;
typedef __attribute__((ext_vector_type(4))) unsigned uvec4;

// ---------- bf16 helpers (RNE) ----------
__device__ __forceinline__ short bf16r(float v) {
    unsigned u = __float_as_uint(v);
    u = (u + 0x7FFFu + ((u >> 16) & 1u)) >> 16;
    return (short)u;
}
__device__ __forceinline__ unsigned pack_bf16x2(float a, float b) {
    unsigned ua = __float_as_uint(a);
    unsigned ub = __float_as_uint(b);
    ua = (ua + 0x7FFFu + ((ua >> 16) & 1u)) >> 16;
    ub = (ub + 0x7FFFu + ((ub >> 16) & 1u)) >> 16;
    return ua | (ub << 16);
}
__device__ __forceinline__ float2 unpack_bf16x2(unsigned v) {
    float2 r;
    r.x = __uint_as_float(v << 16);
    r.y = __uint_as_float(v & 0xFFFF0000u);
    return r;
}
__device__ __forceinline__ float4 unpack_bf16x4(uint2 v) {
    float4 r;
    r.x = __uint_as_float(v.x << 16);
    r.y = __uint_as_float(v.x & 0xFFFF0000u);
    r.z = __uint_as_float(v.y << 16);
    r.w = __uint_as_float(v.y & 0xFFFF0000u);
    return r;
}
struct f8 { float4 a, b; };
__device__ __forceinline__ f8 unpack_bf16x8(uint4 q) {
    f8 r;
    r.a.x = __uint_as_float(q.x << 16);
    r.a.y = __uint_as_float(q.x & 0xFFFF0000u);
    r.a.z = __uint_as_float(q.y << 16);
    r.a.w = __uint_as_float(q.y & 0xFFFF0000u);
    r.b.x = __uint_as_float(q.z << 16);
    r.b.y = __uint_as_float(q.z & 0xFFFF0000u);
    r.b.z = __uint_as_float(q.w << 16);
    r.b.w = __uint_as_float(q.w & 0xFFFF0000u);
    return r;
}
__device__ __forceinline__ float4 sel4(bool c, float4 v) {
    float4 r;
    r.x = c ? v.x : 0.0f; r.y = c ? v.y : 0.0f;
    r.z = c ? v.z : 0.0f; r.w = c ? v.w : 0.0f;
    return r;
}

// ---------- fused A: zgemm (0..781) | inv (782..831) | bucketize (832..1081) ----------
__global__ __launch_bounds__(256) void fused_A(const float* __restrict__ x,
                                               const int* __restrict__ esrc,
                                               const int* __restrict__ edst,
                                               const int* __restrict__ cidx,
                                               const float* __restrict__ W,
                                               int* __restrict__ ccnt,
                                               unsigned short* __restrict__ zs,
                                               unsigned short* __restrict__ cinv,
                                               int* __restrict__ gbcnt,
                                               unsigned* __restrict__ gbuck) {
    __shared__ int bcnt[NBKT];
    __shared__ int bbase[NBKT];
    int lane = threadIdx.x & 63;
    int wv = threadIdx.x >> 6;

    if (blockIdx.x < ZB) {
        // ---- zgemm UNSCALED: zs[n][o] = bf16( dot(x[n], W[o]) ), 1 tile/wave ----
        int gw = blockIdx.x * 4 + wv;                 // 0..3127
        if (gw >= N_NODES / 16) return;
        int q = lane >> 4, r16 = lane & 15;

        short8 bfr[3][4];
        #pragma unroll
        for (int t = 0; t < 3; t++) {
            int o = t * 16 + r16;
            #pragma unroll
            for (int s = 0; s < 4; s++) {
                short8 f = {0, 0, 0, 0, 0, 0, 0, 0};
                if (o < NOUT) {
                    const float* wp = W + o * DIM + s * 32 + q * 8;
                    float4 w0 = *(const float4*)wp;
                    float4 w1 = *(const float4*)(wp + 4);
                    f[0] = bf16r(w0.x); f[1] = bf16r(w0.y);
                    f[2] = bf16r(w0.z); f[3] = bf16r(w0.w);
                    f[4] = bf16r(w1.x); f[5] = bf16r(w1.y);
                    f[6] = bf16r(w1.z); f[7] = bf16r(w1.w);
                }
                bfr[t][s] = f;
            }
        }

        int tile = gw;
        int node = tile * 16 + r16;
        short8 af[4];
        #pragma unroll
        for (int s = 0; s < 4; s++) {
            const fvec4* xp = (const fvec4*)(x + (size_t)node * DIM + s * 32 + q * 8);
            fvec4 a0 = *xp;                       // normal load: x is L3-resident
            fvec4 a1 = *(xp + 1);
            short8 f;
            f[0] = bf16r(a0.x); f[1] = bf16r(a0.y);
            f[2] = bf16r(a0.z); f[3] = bf16r(a0.w);
            f[4] = bf16r(a1.x); f[5] = bf16r(a1.y);
            f[6] = bf16r(a1.z); f[7] = bf16r(a1.w);
            af[s] = f;
        }

        fvec4 acc0 = {0, 0, 0, 0}, acc1 = {0, 0, 0, 0}, acc2 = {0, 0, 0, 0};
        #pragma unroll
        for (int s = 0; s < 4; s++) {
            acc0 = __builtin_amdgcn_mfma_f32_16x16x32_bf16(af[s], bfr[0][s], acc0, 0, 0, 0);
            acc1 = __builtin_amdgcn_mfma_f32_16x16x32_bf16(af[s], bfr[1][s], acc1, 0, 0, 0);
            acc2 = __builtin_amdgcn_mfma_f32_16x16x32_bf16(af[s], bfr[2][s], acc2, 0, 0, 0);
        }

        // NORMAL stores (no nt): a wave writes every byte of its 16 rows, so L2
        // write-combines full lines; zs is read by build_scale next — keep it cached.
        #pragma unroll
        for (int r = 0; r < 4; r++) {
            int nd = tile * 16 + q * 4 + r;
            unsigned short* zrow = zs + (size_t)nd * NOUT;
            zrow[r16] = (unsigned short)bf16r(acc0[r]);
            zrow[16 + r16] = (unsigned short)bf16r(acc1[r]);
            if (r16 < 8)
                zrow[32 + r16] = (unsigned short)bf16r(acc2[r]);
        }
    } else if (blockIdx.x < ZB + INVB) {
        // ---- inverse cluster list: cinv[c][pos] = node ----
        int t0 = (blockIdx.x - ZB) * 256 + threadIdx.x;
        for (int i = t0; i < N_NODES; i += INVB * 256) {
            int c = cidx[i];
            int pos = atomicAdd(&ccnt[c], 1);
            if (pos < CSLOT) cinv[c * CSLOT + pos] = (unsigned short)i;
        }
    } else {
        // ---- bucketize: per-block LDS histogram -> 1 global atomic per (block,bucket) ----
        int fb = blockIdx.x - ZB - INVB;             // 0..249
        const ivec4* src4 = (const ivec4*)esrc;
        const ivec4* dst4 = (const ivec4*)edst;
        int q0 = fb * EPB4;

        for (int i = threadIdx.x; i < NBKT; i += 256) bcnt[i] = 0;
        __syncthreads();

        // scan 1: histogram dst>>7 into LDS
        for (int i = threadIdx.x; i < EPB4; i += 256) {
            ivec4 d4 = dst4[q0 + i];
            atomicAdd(&bcnt[d4.x >> 7], 1);
            atomicAdd(&bcnt[d4.y >> 7], 1);
            atomicAdd(&bcnt[d4.z >> 7], 1);
            atomicAdd(&bcnt[d4.w >> 7], 1);
        }
        __syncthreads();

        // reserve global ranges (one device atomic per non-empty bucket)
        for (int bk = threadIdx.x; bk < NBKT; bk += 256) {
            int c = bcnt[bk];
            bbase[bk] = c ? atomicAdd(&gbcnt[bk * GB_STR], c) : 0;
        }
        __syncthreads();
        for (int i = threadIdx.x; i < NBKT; i += 256) bcnt[i] = 0;
        __syncthreads();

        // scan 2: write packed (dst<<16)|src into reserved ranges (normal stores: L2-resident
        // for build_scale — nt here was the round-7 regression)
        for (int i = threadIdx.x; i < EPB4; i += 256) {
            ivec4 d4 = dst4[q0 + i];
            ivec4 s4 = src4[q0 + i];
            {
                int bk = d4.x >> 7; int idx = atomicAdd(&bcnt[bk], 1);
                unsigned p = (unsigned)(bbase[bk] + idx);
                if (p < BCAP) gbuck[(size_t)bk * BCAP + p] = ((unsigned)d4.x << 16) | (unsigned)s4.x;
            }
            {
                int bk = d4.y >> 7; int idx = atomicAdd(&bcnt[bk], 1);
                unsigned p = (unsigned)(bbase[bk] + idx);
                if (p < BCAP) gbuck[(size_t)bk * BCAP + p] = ((unsigned)d4.y << 16) | (unsigned)s4.y;
            }
            {
                int bk = d4.z >> 7; int idx = atomicAdd(&bcnt[bk], 1);
                unsigned p = (unsigned)(bbase[bk] + idx);
                if (p < BCAP) gbuck[(size_t)bk * BCAP + p] = ((unsigned)d4.z << 16) | (unsigned)s4.z;
            }
            {
                int bk = d4.w >> 7; int idx = atomicAdd(&bcnt[bk], 1);
                unsigned p = (unsigned)(bbase[bk] + idx);
                if (p < BCAP) gbuck[(size_t)bk * BCAP + p] = ((unsigned)d4.w << 16) | (unsigned)s4.w;
            }
        }
    }
}

// ---------- build: bucket -> slot CSR staged in LDS (coalesced out) + cnt + zd scale ------
__global__ __launch_bounds__(256) void build_scale(const unsigned* __restrict__ gbuck,
                                                   const int* __restrict__ gbcnt,
                                                   const uint2* __restrict__ zs2,
                                                   int* __restrict__ cnt,
                                                   unsigned short* __restrict__ slot,
                                                   uint2* __restrict__ zd2) {
    __shared__ int c128[128];
    __shared__ unsigned short sl[128 * SLOTS];   // 16 KB staged slot rows
    int tid = threadIdx.x;
    int b = blockIdx.x;
    if (tid < 128) c128[tid] = 0;
    __syncthreads();
    int m = gbcnt[b * GB_STR];
    if (m > BCAP) m = BCAP;
    const unsigned* bk = gbuck + (size_t)b * BCAP;
    for (int i = tid; i < m; i += 256) {
        unsigned e = bk[i];                      // normal load: gbuck is L2-resident
        int d7 = (int)(e >> 16) & 127;
        int pos = atomicAdd(&c128[d7], 1);
        if (pos < SLOTS) sl[(d7 << 6) + pos] = (unsigned short)(e & 0xFFFFu);
    }
    __syncthreads();
    // stream slot rows out coalesced, NORMAL stores (hop_all reads slot next — keep cached);
    // CLAMP to valid rows (round-6 overrun bug)
    {
        int rows = N_NODES - (b << 7);
        if (rows > 128) rows = 128;
        int n4 = rows * (SLOTS / 8);             // 8 x uvec4 per row
        const uvec4* s4 = (const uvec4*)sl;
        uvec4* g4 = (uvec4*)(slot + ((size_t)(b << 7)) * SLOTS);
        for (int i = tid; i < n4; i += 256)
            g4[i] = s4[i];
    }
    int n0 = b << 7;
    if (tid < 128) {
        int n = n0 + tid;
        if (n < N_NODES) cnt[n] = c128[tid];
    }
    // fused scale: zd[n] = bf16( rsqrt(cnt[n]+1) * zs[n] ) for this block's 128 rows
    for (int i = tid; i < 128 * 10; i += 256) {
        int r = i / 10;
        int n = n0 + r;
        if (n < N_NODES) {
            int k = i - r * 10;
            float dn = rsqrtf((float)(c128[r] + 1));
            float4 f = unpack_bf16x4(zs2[(size_t)n * 10 + k]);
            uint2 p;
            p.x = pack_bf16x2(dn * f.x, dn * f.y);
            p.y = pack_bf16x2(dn * f.z, dn * f.w);
            zd2[(size_t)n * 10 + k] = p;
        }
    }
}

// ---------- hop1 (40-dim): 12 nodes/wave, 5 lanes x uint4, 8 gathers in flight ----------
// v1[n] = dn^2 * ( zd[n] + sum_s zd[s] )   (zd pre-scaled by dinv)
__global__ __launch_bounds__(256) void hop_all(const uint4* __restrict__ zd4,
                                               uint4* __restrict__ v14,
                                               const uint4* __restrict__ slot4,
                                               const int* __restrict__ cnt) {
    int lane = threadIdx.x & 63;
    int wv = threadIdx.x >> 6;
    int g = lane / 5;                      // 0..12 (lanes 60-63 idle)
    int k = lane - g * 5;                  // 0..4, 16B each -> 80B row
    int n = blockIdx.x * 48 + wv * 12 + g;
    if (g >= 12 || n >= N_NODES) return;
    int c = cnt[n];
    int m = (c < SLOTS) ? c : SLOTS;
    float s = 1.0f / (float)(c + 1);       // dinv^2
    f8 self = unpack_bf16x8(zd4[(size_t)n * 5 + k]);   // already dinv-scaled
    float4 aA = self.a, aB = self.b;
    float4 bA = {0, 0, 0, 0}, bB = {0, 0, 0, 0};
    const uint4* srow = slot4 + (size_t)n * 8;         // 64 slots = 8 uint4
    int j = 0;
    for (; j + 8 <= m; j += 8) {           // full chunk: 1 slot load -> 8 gathers in flight
        uint4 s8 = srow[j >> 3];
        f8 f0 = unpack_bf16x8(zd4[(size_t)(s8.x & 0xFFFFu) * 5 + k]);
        f8 f1 = unpack_bf16x8(zd4[(size_t)(s8.x >> 16) * 5 + k]);
        f8 f2 = unpack_bf16x8(zd4[(size_t)(s8.y & 0xFFFFu) * 5 + k]);
        f8 f3 = unpack_bf16x8(zd4[(size_t)(s8.y >> 16) * 5 + k]);
        f8 f4 = unpack_bf16x8(zd4[(size_t)(s8.z & 0xFFFFu) * 5 + k]);
        f8 f5 = unpack_bf16x8(zd4[(size_t)(s8.z >> 16) * 5 + k]);
        f8 f6 = unpack_bf16x8(zd4[(size_t)(s8.w & 0xFFFFu) * 5 + k]);
        f8 f7 = unpack_bf16x8(zd4[(size_t)(s8.w >> 16) * 5 + k]);
        aA = aA + ((f0.a + f1.a) + (f4.a + f5.a));
        aB = aB + ((f0.b + f1.b) + (f4.b + f5.b));
        bA = bA + ((f2.a + f3.a) + (f6.a + f7.a));
        bB = bB + ((f2.b + f3.b) + (f6.b + f7.b));
    }
    if (j < m) {                            // partial chunk: clamp idx (OOB-safe), select adds (NaN-safe)
        int rem = m - j;                    // 1..7, uniform within the 5-lane group
        uint4 s8 = srow[j >> 3];
        unsigned i0 = s8.x & 0xFFFFu;
        unsigned i1 = (rem > 1) ? (s8.x >> 16) : 0u;
        unsigned i2 = (rem > 2) ? (s8.y & 0xFFFFu) : 0u;
        unsigned i3 = (rem > 3) ? (s8.y >> 16) : 0u;
        unsigned i4 = (rem > 4) ? (s8.z & 0xFFFFu) : 0u;
        unsigned i5 = (rem > 5) ? (s8.z >> 16) : 0u;
        unsigned i6 = (rem > 6) ? (s8.w & 0xFFFFu) : 0u;
        f8 f0 = unpack_bf16x8(zd4[(size_t)i0 * 5 + k]);
        f8 f1 = unpack_bf16x8(zd4[(size_t)i1 * 5 + k]);
        f8 f2 = unpack_bf16x8(zd4[(size_t)i2 * 5 + k]);
        f8 f3 = unpack_bf16x8(zd4[(size_t)i3 * 5 + k]);
        f8 f4 = unpack_bf16x8(zd4[(size_t)i4 * 5 + k]);
        f8 f5 = unpack_bf16x8(zd4[(size_t)i5 * 5 + k]);
        f8 f6 = unpack_bf16x8(zd4[(size_t)i6 * 5 + k]);
        aA = aA + f0.a;                     // rem >= 1 always
        aB = aB + f0.b;
        bA = bA + sel4(rem > 1, f1.a) + sel4(rem > 3, f3.a) + sel4(rem > 5, f5.a);
        bB = bB + sel4(rem > 1, f1.b) + sel4(rem > 3, f3.b) + sel4(rem > 5, f5.b);
        aA = aA + sel4(rem > 2, f2.a) + sel4(rem > 4, f4.a) + sel4(rem > 6, f6.a);
        aB = aB + sel4(rem > 2, f2.b) + sel4(rem > 4, f4.b) + sel4(rem > 6, f6.b);
    }
    float4 rA = aA + bA;
    float4 rB = aB + bB;
    uint4 o;
    o.x = pack_bf16x2(s * rA.x, s * rA.y);
    o.y = pack_bf16x2(s * rA.z, s * rA.w);
    o.z = pack_bf16x2(s * rB.x, s * rB.y);
    o.w = pack_bf16x2(s * rB.z, s * rB.w);
    v14[(size_t)n * 5 + k] = o;
}

// ---------- fused hop2(rep) + bias + log_softmax + scatter to members ----------
__global__ __launch_bounds__(256) void rep_scatter(const unsigned* __restrict__ v1,
                                                   const unsigned short* __restrict__ slot,
                                                   const int* __restrict__ cnt,
                                                   const int* __restrict__ ccnt,
                                                   const unsigned short* __restrict__ cinv,
                                                   const int* __restrict__ rep_idx,
                                                   const float2* __restrict__ b2,
                                                   float2* __restrict__ out2) {
    int lane = threadIdx.x & 63;
    int wv = threadIdx.x >> 6;
    int c = blockIdx.x * 4 + wv;
    if (c >= N_CLUST) return;
    int n = rep_idx[c];
    int cn = cnt[n];
    int m = (cn < SLOTS) ? cn : SLOTS;
    float dn = rsqrtf((float)(cn + 1));
    int g = lane / 20;
    int k = lane - g * 20;
    float2 acc; acc.x = 0.0f; acc.y = 0.0f;
    if (g == 0) acc = unpack_bf16x2(v1[n * 20 + k]);   // self
    if (g < 3) {
        int base = n * SLOTS;
        for (int j = g; j < m; j += 3) {
            float2 f = unpack_bf16x2(v1[(int)slot[base + j] * 20 + k]);
            acc.x += f.x; acc.y += f.y;
        }
    }
    float t1x = __shfl(acc.x, lane + 20), t1y = __shfl(acc.y, lane + 20);
    float t2x = __shfl(acc.x, lane + 40), t2y = __shfl(acc.y, lane + 40);
    bool act = (lane < 20);
    float2 h; h.x = 0.0f; h.y = 0.0f;
    if (act) {
        float2 bb = b2[k];
        h.x = dn * (acc.x + t1x + t2x) + bb.x;
        h.y = dn * (acc.y + t1y + t2y) + bb.y;
    }
    float mx = act ? fmaxf(h.x, h.y) : -INFINITY;
    #pragma unroll
    for (int off = 32; off; off >>= 1) mx = fmaxf(mx, __shfl_xor(mx, off));
    float e = act ? (expf(h.x - mx) + expf(h.y - mx)) : 0.0f;
    #pragma unroll
    for (int off = 32; off; off >>= 1) e += __shfl_xor(e, off);
    float lg = mx + logf(e);
    float2 o; o.x = h.x - lg; o.y = h.y - lg;
    // broadcast o across the three 20-lane groups, scatter 3 members at a time
    float ox = __shfl(o.x, k);
    float oy = __shfl(o.y, k);
    int mc = ccnt[c];
    if (mc > CSLOT) mc = CSLOT;
    const unsigned short* mem = cinv + c * CSLOT;
    if (g < 3) {
        float2 ob; ob.x = ox; ob.y = oy;
        for (int idx = g; idx < mc; idx += 3) {
            int node = (int)mem[idx];
            out2[(size_t)node * 20 + k] = ob;
        }
    }
}

extern "C" void kernel_launch(void* const* d_in, const int* in_sizes, int n_in,
                              void* d_out, int out_size, void* d_ws, size_t ws_size,
                              hipStream_t stream) {
    const float* x    = (const float*)d_in[0];
    const int*   esrc = (const int*)d_in[1];
    const int*   edst = ((const int*)d_in[1]) + N_EDGES;
    const int*   cidx = (const int*)d_in[2];
    const int*   ridx = (const int*)d_in[3];
    const float* W    = (const float*)d_in[4];
    const float* b    = (const float*)d_in[5];
    float* out = (float*)d_out;

    char* ws = (char*)d_ws;
    size_t off = 0;
    auto alloc = [&](size_t bytes) { char* p = ws + off; off += (bytes + 255) & ~size_t(255); return p; };
    int*            cnt   = (int*)alloc((N_NODES + N_CLUST + NBKT * GB_STR) * 4);
    int*            ccnt  = cnt + N_NODES;
    int*            gbcnt = ccnt + N_CLUST;
    unsigned short* slot  = (unsigned short*)alloc((size_t)N_NODES * SLOTS * 2);  // 6.4 MB
    unsigned short* zs    = (unsigned short*)alloc((size_t)N_NODES * NOUT * 2);   // 4 MB
    unsigned short* zd    = (unsigned short*)alloc((size_t)N_NODES * NOUT * 2);   // 4 MB
    unsigned*       v1    = (unsigned*)alloc((size_t)N_NODES * (NOUT / 2) * 4);   // 4 MB
    unsigned short* cinv  = (unsigned short*)alloc((size_t)N_CLUST * CSLOT * 2);  // 640 KB
    unsigned*       gbuck = (unsigned*)alloc((size_t)NBKT * BCAP * 4);            // 4 MB
    (void)ws_size; (void)in_sizes; (void)n_in; (void)out_size;

    // cnt is fully rewritten by build_scale; only ccnt + gbcnt need zeroing
    (void)hipMemsetAsync(ccnt, 0, (N_CLUST + NBKT * GB_STR) * 4, stream);

    fused_A<<<GRID_A, 256, 0, stream>>>(x, esrc, edst, cidx, W,
                                        ccnt, zs, cinv, gbcnt, gbuck);
    build_scale<<<NBKT, 256, 0, stream>>>(gbuck, gbcnt, (const uint2*)zs,
                                          cnt, slot, (uint2*)zd);
    hop_all<<<(N_NODES + 47) / 48, 256, 0, stream>>>((const uint4*)zd, (uint4*)v1,
                                                     (const uint4*)slot, cnt);
    rep_scatter<<<(N_CLUST + 3) / 4, 256, 0, stream>>>((const unsigned*)v1, slot, cnt,
                                                       ccnt, cinv, ridx,
                                                       (const float2*)b, (float2*)out);
}